// Round 1
// baseline (30.079 us; speedup 1.0000x reference)
//
#include <hip/hip_runtime.h>

// LengthRegulator: B=32, N=256, D=384, max_dur=2048 (fixed by setup_inputs)
constexpr int B_   = 32;
constexpr int N_   = 256;
constexpr int MD_  = 2048;
constexpr int D_   = 384;
constexpr int D4_  = D_ / 4;          // 96 float4 per row
constexpr int NBLK = 2048;
constexpr int NTHR = 256;
constexpr int TOTAL_E = B_ * MD_ * D4_;        // 6,291,456 float4 elements
constexpr int CHUNK   = TOTAL_E / NBLK;        // 3072 per block (exact)

__global__ __launch_bounds__(NTHR) void lr_kernel(
    const float4* __restrict__ x4,      // [B][N][D4]
    const int*    __restrict__ dur,     // [B][N]
    float4*       __restrict__ out4,    // [B][MD][D4]
    float*        __restrict__ out_total) // [B]
{
    __shared__ int cum[B_ * N_];        // 32 KB: per-batch inclusive cumsum

    const int t    = threadIdx.x;
    const int wave = t >> 6;
    const int lane = t & 63;

    // --- per-batch inclusive cumsum, one wave per batch (4 waves -> 8 batches each)
    for (int b = wave; b < B_; b += 4) {
        int4 dv = reinterpret_cast<const int4*>(dur)[b * (N_ / 4) + lane];
        int s0 = dv.x;
        int s1 = s0 + dv.y;
        int s2 = s1 + dv.z;
        int s3 = s2 + dv.w;
        int s = s3;
        #pragma unroll
        for (int o = 1; o < 64; o <<= 1) {
            int u = __shfl_up(s, o);    // wave64 scan
            if (lane >= o) s += u;
        }
        const int excl = s - s3;        // exclusive prefix of this lane's 4-chunk
        int4 c4 = make_int4(s0 + excl, s1 + excl, s2 + excl, s3 + excl);
        reinterpret_cast<int4*>(cum)[b * (N_ / 4) + lane] = c4;
    }
    __syncthreads();

    if (blockIdx.x == 0 && t < B_) {
        out_total[t] = (float)cum[t * N_ + N_ - 1];
    }

    // --- gather: contiguous CHUNK of float4 output elements per block
    const int base = blockIdx.x * CHUNK;
    #pragma unroll
    for (int i = 0; i < CHUNK / NTHR; ++i) {   // 12 iterations
        const int l   = base + i * NTHR + t;   // flat float4 index
        const int d4  = l % D4_;
        const int row = l / D4_;                // b*MD + pos
        const int b   = row >> 11;              // MD_ = 2048
        const int pos = row & (MD_ - 1);

        const int* cb = &cum[b * N_];
        const int total_b = cb[N_ - 1];

        float4 v = make_float4(0.f, 0.f, 0.f, 0.f);
        if (pos < total_b) {
            // branchless upper_bound over 256 sorted ints:
            // lo = count of elements <= pos (answer <= 255 since pos < cum[255])
            int lo = 0;
            #pragma unroll
            for (int w = 128; w > 0; w >>= 1) {
                if (cb[lo + w - 1] <= pos) lo += w;
            }
            v = x4[(b * N_ + lo) * D4_ + d4];
        }
        out4[l] = v;
    }
}

extern "C" void kernel_launch(void* const* d_in, const int* in_sizes, int n_in,
                              void* d_out, int out_size, void* d_ws, size_t ws_size,
                              hipStream_t stream) {
    const float4* x4  = (const float4*)d_in[0];
    const int*    dur = (const int*)d_in[1];
    // d_in[2] = max_dur scalar (2048, fixed by the problem instance)

    float*  out       = (float*)d_out;
    float*  out_total = out + (size_t)B_ * MD_ * D_;  // totals appended after out
    float4* out4      = (float4*)d_out;

    lr_kernel<<<NBLK, NTHR, 0, stream>>>(x4, dur, out4, out_total);
}

// Round 3
// 26.691 us; speedup vs baseline: 1.1269x; 1.1269x over previous
//
#include <hip/hip_runtime.h>

// LengthRegulator: B=32, N=256, D=384, max_dur=2048 (fixed by setup_inputs)
constexpr int B_   = 32;
constexpr int N_   = 256;
constexpr int MD_  = 2048;
constexpr int D_   = 384;
constexpr int D4_  = D_ / 4;          // 96 float4 per row
constexpr int NBLK = 2048;
constexpr int NTHR = 256;
constexpr int TOTAL_E = B_ * MD_ * D4_;        // 6,291,456 float4 elements
constexpr int CHUNK   = TOTAL_E / NBLK;        // 3072 per block = 32 rows (exact)
// 64 blocks per batch: CHUNK*64 == MD_*D4_

typedef float  f32x4 __attribute__((ext_vector_type(4)));  // native vec for nt-store
typedef int    i32x4 __attribute__((ext_vector_type(4)));

__global__ __launch_bounds__(NTHR) void lr_kernel(
    const f32x4* __restrict__ x4,       // [B][N][D4]
    const int*   __restrict__ dur,      // [B][N]
    f32x4*       __restrict__ out4,     // [B][MD][D4]
    float*       __restrict__ out_total) // [B]
{
    __shared__ int cum[N_];             // 1 KB: this batch's inclusive cumsum

    const int t = threadIdx.x;
    const int b = blockIdx.x >> 6;      // 64 consecutive blocks share a batch

    // --- inclusive cumsum of this batch's 256 durations, wave 0 only
    if (t < 64) {
        i32x4 dv = reinterpret_cast<const i32x4*>(dur)[b * (N_ / 4) + t];
        int s0 = dv.x;
        int s1 = s0 + dv.y;
        int s2 = s1 + dv.z;
        int s3 = s2 + dv.w;
        int s = s3;
        #pragma unroll
        for (int o = 1; o < 64; o <<= 1) {
            int u = __shfl_up(s, o);    // wave64 inclusive scan of 4-chunk sums
            if (t >= o) s += u;
        }
        const int excl = s - s3;        // exclusive prefix for this lane's chunk
        i32x4 c4; c4.x = s0 + excl; c4.y = s1 + excl; c4.z = s2 + excl; c4.w = s3 + excl;
        reinterpret_cast<i32x4*>(cum)[t] = c4;
    }
    __syncthreads();

    const int total_b = cum[N_ - 1];
    if ((blockIdx.x & 63) == 0 && t == 0) {
        out_total[b] = (float)total_b;
    }

    // --- gather: contiguous CHUNK of float4 output elements per block
    const int base = blockIdx.x * CHUNK;
    #pragma unroll
    for (int i = 0; i < CHUNK / NTHR; ++i) {   // 12 iterations
        const int l   = base + i * NTHR + t;   // flat float4 index
        const int d4  = l % D4_;
        const int row = l / D4_;               // b*MD + pos
        const int pos = row & (MD_ - 1);

        f32x4 v = (f32x4)0.f;
        if (pos < total_b) {
            // branchless upper_bound over 256 sorted ints:
            // lo = count of elements <= pos (answer <= 255 since pos < cum[255])
            int lo = 0;
            #pragma unroll
            for (int w = 128; w > 0; w >>= 1) {
                if (cum[lo + w - 1] <= pos) lo += w;
            }
            v = x4[(b * N_ + lo) * D4_ + d4];
        }
        __builtin_nontemporal_store(v, &out4[l]);  // write-once stream, keep x in L2
    }
}

extern "C" void kernel_launch(void* const* d_in, const int* in_sizes, int n_in,
                              void* d_out, int out_size, void* d_ws, size_t ws_size,
                              hipStream_t stream) {
    const f32x4* x4  = (const f32x4*)d_in[0];
    const int*   dur = (const int*)d_in[1];
    // d_in[2] = max_dur scalar (2048, fixed by the problem instance)

    float* out       = (float*)d_out;
    float* out_total = out + (size_t)B_ * MD_ * D_;  // totals appended after out
    f32x4* out4      = (f32x4*)d_out;

    lr_kernel<<<NBLK, NTHR, 0, stream>>>(x4, dur, out4, out_total);
}

// Round 4
// 25.491 us; speedup vs baseline: 1.1800x; 1.0471x over previous
//
#include <hip/hip_runtime.h>

// LengthRegulator: B=32, N=256, D=384, max_dur=2048 (fixed by setup_inputs)
constexpr int B_   = 32;
constexpr int N_   = 256;
constexpr int MD_  = 2048;
constexpr int D_   = 384;
constexpr int D4_  = D_ / 4;          // 96 float4 per row
constexpr int NBLK = 2048;
constexpr int NTHR = 256;
constexpr int TOTAL_E = B_ * MD_ * D4_;        // 6,291,456 float4 elements
constexpr int CHUNK   = TOTAL_E / NBLK;        // 3072 per block = 32 rows (exact)
constexpr int ROWS    = CHUNK / D4_;           // 32 output rows per block
// 64 blocks per batch: CHUNK*64 == MD_*D4_

typedef float  f32x4 __attribute__((ext_vector_type(4)));  // native vec for nt-store
typedef int    i32x4 __attribute__((ext_vector_type(4)));

__global__ __launch_bounds__(NTHR) void lr_kernel(
    const f32x4* __restrict__ x4,       // [B][N][D4]
    const int*   __restrict__ dur,      // [B][N]
    f32x4*       __restrict__ out4,     // [B][MD][D4]
    float*       __restrict__ out_total) // [B]
{
    __shared__ int cum[N_];             // 1 KB: this batch's inclusive cumsum
    __shared__ int srcrow[ROWS];        // per output row: source row or -1 (zero row)

    const int t = threadIdx.x;
    const int b = blockIdx.x >> 6;      // 64 consecutive blocks share a batch

    // --- wave 0: inclusive cumsum of this batch's 256 durations
    if (t < 64) {
        i32x4 dv = reinterpret_cast<const i32x4*>(dur)[b * (N_ / 4) + t];
        int s0 = dv.x;
        int s1 = s0 + dv.y;
        int s2 = s1 + dv.z;
        int s3 = s2 + dv.w;
        int s = s3;
        #pragma unroll
        for (int o = 1; o < 64; o <<= 1) {
            int u = __shfl_up(s, o);    // wave64 inclusive scan of 4-chunk sums
            if (t >= o) s += u;
        }
        const int excl = s - s3;        // exclusive prefix for this lane's chunk
        i32x4 c4; c4.x = s0 + excl; c4.y = s1 + excl; c4.z = s2 + excl; c4.w = s3 + excl;
        reinterpret_cast<i32x4*>(cum)[t] = c4;
    }
    // --- wave 0, lanes 0-31: one binary search per output row of this block
    //     (same-wave LDS RAW on cum[]: compiler inserts lgkmcnt wait)
    if (t < ROWS) {
        const int pos = ((blockIdx.x & 63) * ROWS) + t;
        const int total_b = cum[N_ - 1];
        int lo = 0;
        #pragma unroll
        for (int w = 128; w > 0; w >>= 1) {    // lo = count of cum[] <= pos
            if (cum[lo + w - 1] <= pos) lo += w;
        }
        srcrow[t] = (pos < total_b) ? lo : -1; // pos<total => lo<=255
        if (t == 0 && (blockIdx.x & 63) == 0) {
            out_total[b] = (float)total_b;
        }
    }
    __syncthreads();

    // --- gather: contiguous CHUNK of float4 output elements per block
    const int base = blockIdx.x * CHUNK;
    const f32x4* __restrict__ xb = x4 + (size_t)b * (N_ * D4_);
    #pragma unroll
    for (int i = 0; i < CHUNK / NTHR; ++i) {   // 12 iterations
        const int li = i * NTHR + t;           // 0..3071 within block
        const int q  = li / D4_;               // local row 0..31
        const int d4 = li - q * D4_;
        const int r  = srcrow[q];              // broadcast LDS read (<=2 rows/wave)
        f32x4 v = (f32x4)0.f;
        if (r >= 0) v = xb[r * D4_ + d4];      // predicated: no loads in zero region
        __builtin_nontemporal_store(v, &out4[base + li]);  // streaming write
    }
}

extern "C" void kernel_launch(void* const* d_in, const int* in_sizes, int n_in,
                              void* d_out, int out_size, void* d_ws, size_t ws_size,
                              hipStream_t stream) {
    const f32x4* x4  = (const f32x4*)d_in[0];
    const int*   dur = (const int*)d_in[1];
    // d_in[2] = max_dur scalar (2048, fixed by the problem instance)

    float* out       = (float*)d_out;
    float* out_total = out + (size_t)B_ * MD_ * D_;  // totals appended after out
    f32x4* out4      = (f32x4*)d_out;

    lr_kernel<<<NBLK, NTHR, 0, stream>>>(x4, dur, out4, out_total);
}

// Round 5
// 25.131 us; speedup vs baseline: 1.1969x; 1.0143x over previous
//
#include <hip/hip_runtime.h>

// LengthRegulator: B=32, N=256, D=384, max_dur=2048 (fixed by setup_inputs)
constexpr int B_   = 32;
constexpr int N_   = 256;
constexpr int MD_  = 2048;
constexpr int D_   = 384;
constexpr int D4_  = D_ / 4;          // 96 float4 per row
constexpr int NBLK = 2048;
constexpr int NTHR = 256;
constexpr int TOTAL_E = B_ * MD_ * D4_;        // 6,291,456 float4 elements
constexpr int CHUNK   = TOTAL_E / NBLK;        // 3072 per block = 32 rows (exact)
constexpr int ROWS    = CHUNK / D4_;           // 32 output rows per block
// 64 blocks per batch: CHUNK*64 == MD_*D4_

typedef float  f32x4 __attribute__((ext_vector_type(4)));  // native vec for nt-store
typedef int    i32x4 __attribute__((ext_vector_type(4)));

__global__ __launch_bounds__(NTHR) void lr_kernel(
    const f32x4* __restrict__ x4,       // [B][N][D4]
    const int*   __restrict__ dur,      // [B][N]
    f32x4*       __restrict__ out4,     // [B][MD][D4]
    float*       __restrict__ out_total) // [B]
{
    __shared__ int cum[N_];             // 1 KB: this batch's inclusive cumsum
    __shared__ int srcrow[ROWS];        // per output row: source row or -1 (zero row)

    const int t = threadIdx.x;
    // XCD-chunked bijective swizzle (2048 % 8 == 0): blocks with bid%8==c
    // form one contiguous range -> each batch's 64 blocks live on one XCD's L2.
    const int bid = ((blockIdx.x & 7) << 8) + (blockIdx.x >> 3);
    const int b   = bid >> 6;           // 64 consecutive (swizzled) blocks share a batch

    // --- wave 0: inclusive cumsum of this batch's 256 durations
    if (t < 64) {
        i32x4 dv = reinterpret_cast<const i32x4*>(dur)[b * (N_ / 4) + t];
        int s0 = dv.x;
        int s1 = s0 + dv.y;
        int s2 = s1 + dv.z;
        int s3 = s2 + dv.w;
        int s = s3;
        #pragma unroll
        for (int o = 1; o < 64; o <<= 1) {
            int u = __shfl_up(s, o);    // wave64 inclusive scan of 4-chunk sums
            if (t >= o) s += u;
        }
        const int excl = s - s3;        // exclusive prefix for this lane's chunk
        i32x4 c4; c4.x = s0 + excl; c4.y = s1 + excl; c4.z = s2 + excl; c4.w = s3 + excl;
        reinterpret_cast<i32x4*>(cum)[t] = c4;
    }
    // --- wave 0, lanes 0-31: one binary search per output row of this block
    //     (same-wave LDS RAW on cum[]: compiler inserts lgkmcnt wait)
    if (t < ROWS) {
        const int pos = ((bid & 63) * ROWS) + t;
        const int total_b = cum[N_ - 1];
        int lo = 0;
        #pragma unroll
        for (int w = 128; w > 0; w >>= 1) {    // lo = count of cum[] <= pos
            if (cum[lo + w - 1] <= pos) lo += w;
        }
        srcrow[t] = (pos < total_b) ? lo : -1; // pos<total => lo<=255
        if (t == 0 && (bid & 63) == 0) {
            out_total[b] = (float)total_b;
        }
    }
    __syncthreads();

    // --- gather: contiguous CHUNK of float4 output elements per block.
    //     Two half-passes of 6: stage 6 loads in regs, then 6 nt-stores (MLP).
    const int base = bid * CHUNK;
    const f32x4* __restrict__ xb = x4 + (size_t)b * (N_ * D4_);
    #pragma unroll
    for (int h = 0; h < 2; ++h) {
        f32x4 vals[6];
        #pragma unroll
        for (int j = 0; j < 6; ++j) {
            const int li = (h * 6 + j) * NTHR + t;        // 0..3071 within block
            const int q  = ((li >> 5) * 43) >> 7;         // == li/96 for li<3072
            const int d4 = li - q * D4_;
            const int r  = srcrow[q];                     // broadcast LDS read
            vals[j] = (f32x4)0.f;
            if (r >= 0) vals[j] = xb[r * D4_ + d4];       // no loads in zero region
        }
        #pragma unroll
        for (int j = 0; j < 6; ++j) {
            const int li = (h * 6 + j) * NTHR + t;
            __builtin_nontemporal_store(vals[j], &out4[base + li]);
        }
    }
}

extern "C" void kernel_launch(void* const* d_in, const int* in_sizes, int n_in,
                              void* d_out, int out_size, void* d_ws, size_t ws_size,
                              hipStream_t stream) {
    const f32x4* x4  = (const f32x4*)d_in[0];
    const int*   dur = (const int*)d_in[1];
    // d_in[2] = max_dur scalar (2048, fixed by the problem instance)

    float* out       = (float*)d_out;
    float* out_total = out + (size_t)B_ * MD_ * D_;  // totals appended after out
    f32x4* out4      = (f32x4*)d_out;

    lr_kernel<<<NBLK, NTHR, 0, stream>>>(x4, dur, out4, out_total);
}

// Round 6
// 24.142 us; speedup vs baseline: 1.2459x; 1.0410x over previous
//
#include <hip/hip_runtime.h>

// LengthRegulator: B=32, N=256, D=384, max_dur=2048 (fixed by setup_inputs)
constexpr int B_   = 32;
constexpr int N_   = 256;
constexpr int MD_  = 2048;
constexpr int D_   = 384;
constexpr int D4_  = D_ / 4;          // 96 float4 per row
constexpr int NBLK = 2048;
constexpr int NTHR = 256;
constexpr int TOTAL_E = B_ * MD_ * D4_;        // 6,291,456 float4 elements
constexpr int CHUNK   = TOTAL_E / NBLK;        // 3072 float4 = 32 rows per block
constexpr int ROWS    = CHUNK / D4_;           // 32 output rows per block
constexpr int BPB     = 64;                    // blocks per batch
// Row interleave: block j of a batch owns rows {j, j+64, ..., j+64*31}
// -> every block gets the batch-average valid/zero mix (load balance).

typedef float  f32x4 __attribute__((ext_vector_type(4)));  // native vec for nt-store
typedef int    i32x4 __attribute__((ext_vector_type(4)));

__global__ __launch_bounds__(NTHR, 8) void lr_kernel(   // VGPR<=64: 8 blocks/CU resident
    const f32x4* __restrict__ x4,       // [B][N][D4]
    const int*   __restrict__ dur,      // [B][N]
    f32x4*       __restrict__ out4,     // [B][MD][D4]
    float*       __restrict__ out_total) // [B]
{
    __shared__ int cum[N_];             // 1 KB: this batch's inclusive cumsum
    __shared__ int srcrow[ROWS];        // per owned row: source row or -1 (zero row)

    const int t = threadIdx.x;
    // XCD-chunked bijective swizzle (2048 % 8 == 0): each batch's 64 blocks
    // land on one XCD -> its 396 KB x-slice stays in that XCD's L2.
    const int bid = ((blockIdx.x & 7) << 8) + (blockIdx.x >> 3);
    const int b   = bid >> 6;           // batch
    const int j   = bid & (BPB - 1);    // block index within batch

    // --- wave 0: inclusive cumsum of this batch's 256 durations
    if (t < 64) {
        i32x4 dv = reinterpret_cast<const i32x4*>(dur)[b * (N_ / 4) + t];
        int s0 = dv.x;
        int s1 = s0 + dv.y;
        int s2 = s1 + dv.z;
        int s3 = s2 + dv.w;
        int s = s3;
        #pragma unroll
        for (int o = 1; o < 64; o <<= 1) {
            int u = __shfl_up(s, o);    // wave64 inclusive scan of 4-chunk sums
            if (t >= o) s += u;
        }
        const int excl = s - s3;        // exclusive prefix for this lane's chunk
        i32x4 c4; c4.x = s0 + excl; c4.y = s1 + excl; c4.z = s2 + excl; c4.w = s3 + excl;
        reinterpret_cast<i32x4*>(cum)[t] = c4;
    }
    // --- wave 0, lanes 0-31: one binary search per owned row (pos = j + 64*t)
    //     (same-wave LDS RAW on cum[]: compiler inserts lgkmcnt wait)
    if (t < ROWS) {
        const int pos = j + BPB * t;
        const int total_b = cum[N_ - 1];
        int lo = 0;
        #pragma unroll
        for (int w = 128; w > 0; w >>= 1) {    // lo = count of cum[] <= pos
            if (cum[lo + w - 1] <= pos) lo += w;
        }
        srcrow[t] = (pos < total_b) ? lo : -1; // pos<total => lo<=255
        if (t == 0 && j == 0) {
            out_total[b] = (float)total_b;
        }
    }
    __syncthreads();

    // --- gather/zero-fill the 32 owned rows (each row = 96 contiguous float4)
    const f32x4* __restrict__ xb = x4 + (size_t)b * (N_ * D4_);
    f32x4* __restrict__ ob = out4 + (size_t)b * (MD_ * D4_) + j * D4_;  // row j base
    #pragma unroll
    for (int i = 0; i < CHUNK / NTHR; ++i) {   // 12 iterations
        const int li = i * NTHR + t;           // 0..3071 within block
        const int q  = ((li >> 5) * 43) >> 7;  // == li/96 for li<3072 (local row)
        const int d4 = li - q * D4_;
        const int r  = srcrow[q];              // broadcast LDS read (<=2 rows/wave)
        f32x4 v = (f32x4)0.f;
        if (r >= 0) v = xb[r * D4_ + d4];      // predicated: no loads in zero rows
        // output row = j + 64*q  -> offset q*(64*96) + d4 from row-j base
        __builtin_nontemporal_store(v, &ob[q * (BPB * D4_) + d4]);
    }
}

extern "C" void kernel_launch(void* const* d_in, const int* in_sizes, int n_in,
                              void* d_out, int out_size, void* d_ws, size_t ws_size,
                              hipStream_t stream) {
    const f32x4* x4  = (const f32x4*)d_in[0];
    const int*   dur = (const int*)d_in[1];
    // d_in[2] = max_dur scalar (2048, fixed by the problem instance)

    float* out       = (float*)d_out;
    float* out_total = out + (size_t)B_ * MD_ * D_;  // totals appended after out
    f32x4* out4      = (f32x4*)d_out;

    lr_kernel<<<NBLK, NTHR, 0, stream>>>(x4, dur, out4, out_total);
}

// Round 7
// 21.840 us; speedup vs baseline: 1.3772x; 1.1054x over previous
//
#include <hip/hip_runtime.h>

// LengthRegulator: B=32, N=256, D=384, max_dur=2048 (fixed by setup_inputs)
constexpr int B_   = 32;
constexpr int N_   = 256;
constexpr int MD_  = 2048;
constexpr int D_   = 384;
constexpr int D4_  = D_ / 4;          // 96 float4 per row
constexpr int NBLK = 2048;
constexpr int NTHR = 256;
constexpr int TOTAL_E = B_ * MD_ * D4_;        // 6,291,456 float4 elements
constexpr int CHUNK   = TOTAL_E / NBLK;        // 3072 float4 = 32 rows per block
constexpr int ROWS    = CHUNK / D4_;           // 32 output rows per block
constexpr int BPB     = 64;                    // blocks per batch
// Row interleave: block j of a batch owns rows {j, j+64, ..., j+64*31}
// -> every block gets the batch-average valid/zero mix (load balance).

typedef float  f32x4 __attribute__((ext_vector_type(4)));
typedef int    i32x4 __attribute__((ext_vector_type(4)));

__global__ __launch_bounds__(NTHR, 8) void lr_kernel(   // VGPR<=64: 8 blocks/CU resident
    const f32x4* __restrict__ x4,       // [B][N][D4]
    const int*   __restrict__ dur,      // [B][N]
    f32x4*       __restrict__ out4,     // [B][MD][D4]
    float*       __restrict__ out_total) // [B]
{
    __shared__ int cum[N_];             // 1 KB: this batch's inclusive cumsum
    __shared__ int srcrow[ROWS];        // per owned row: source row or -1 (zero row)

    const int t = threadIdx.x;
    // XCD-chunked bijective swizzle (2048 % 8 == 0): each batch's 64 blocks
    // land on one XCD -> its 396 KB x-slice stays in that XCD's L2.
    const int bid = ((blockIdx.x & 7) << 8) + (blockIdx.x >> 3);
    const int b   = bid >> 6;           // batch
    const int j   = bid & (BPB - 1);    // block index within batch

    // --- wave 0: inclusive cumsum of this batch's 256 durations
    if (t < 64) {
        i32x4 dv = reinterpret_cast<const i32x4*>(dur)[b * (N_ / 4) + t];
        int s0 = dv.x;
        int s1 = s0 + dv.y;
        int s2 = s1 + dv.z;
        int s3 = s2 + dv.w;
        int s = s3;
        #pragma unroll
        for (int o = 1; o < 64; o <<= 1) {
            int u = __shfl_up(s, o);    // wave64 inclusive scan of 4-chunk sums
            if (t >= o) s += u;
        }
        const int excl = s - s3;        // exclusive prefix for this lane's chunk
        i32x4 c4; c4.x = s0 + excl; c4.y = s1 + excl; c4.z = s2 + excl; c4.w = s3 + excl;
        reinterpret_cast<i32x4*>(cum)[t] = c4;
    }
    // --- wave 0, lanes 0-31: one binary search per owned row (pos = j + 64*t)
    //     (same-wave LDS RAW on cum[]: compiler inserts lgkmcnt wait)
    if (t < ROWS) {
        const int pos = j + BPB * t;
        const int total_b = cum[N_ - 1];
        int lo = 0;
        #pragma unroll
        for (int w = 128; w > 0; w >>= 1) {    // lo = count of cum[] <= pos
            if (cum[lo + w - 1] <= pos) lo += w;
        }
        srcrow[t] = (pos < total_b) ? lo : -1; // pos<total => lo<=255
        if (t == 0 && j == 0) {
            out_total[b] = (float)total_b;
        }
    }
    __syncthreads();

    // --- gather/zero-fill the 32 owned rows (each row = 96 contiguous float4)
    const f32x4* __restrict__ xb = x4 + (size_t)b * (N_ * D4_);
    f32x4* __restrict__ ob = out4 + (size_t)b * (MD_ * D4_) + j * D4_;  // row j base
    #pragma unroll
    for (int i = 0; i < CHUNK / NTHR; ++i) {   // 12 iterations
        const int li = i * NTHR + t;           // 0..3071 within block
        const int q  = ((li >> 5) * 43) >> 7;  // == li/96 for li<3072 (local row)
        const int d4 = li - q * D4_;
        const int r  = srcrow[q];              // broadcast LDS read (<=2 rows/wave)
        f32x4 v = (f32x4)0.f;
        if (r >= 0) v = xb[r * D4_ + d4];      // predicated: no loads in zero rows
        // output row = j + 64*q  -> offset q*(64*96) + d4 from row-j base
        ob[q * (BPB * D4_) + d4] = v;          // A/B: normal store (was nontemporal)
    }
}

extern "C" void kernel_launch(void* const* d_in, const int* in_sizes, int n_in,
                              void* d_out, int out_size, void* d_ws, size_t ws_size,
                              hipStream_t stream) {
    const f32x4* x4  = (const f32x4*)d_in[0];
    const int*   dur = (const int*)d_in[1];
    // d_in[2] = max_dur scalar (2048, fixed by the problem instance)

    float* out       = (float*)d_out;
    float* out_total = out + (size_t)B_ * MD_ * D_;  // totals appended after out
    f32x4* out4      = (f32x4*)d_out;

    lr_kernel<<<NBLK, NTHR, 0, stream>>>(x4, dur, out4, out_total);
}

// Round 8
// 21.751 us; speedup vs baseline: 1.3829x; 1.0041x over previous
//
#include <hip/hip_runtime.h>

// LengthRegulator: B=32, N=256, D=384, max_dur=2048 (fixed by setup_inputs)
constexpr int B_   = 32;
constexpr int N_   = 256;
constexpr int MD_  = 2048;
constexpr int D_   = 384;
constexpr int D4_  = D_ / 4;          // 96 float4 per row
constexpr int NBLK = 2048;
constexpr int NTHR = 256;
constexpr int TOTAL_E = B_ * MD_ * D4_;        // 6,291,456 float4 elements
constexpr int CHUNK   = TOTAL_E / NBLK;        // 3072 float4 = 32 rows per block
constexpr int ROWS    = CHUNK / D4_;           // 32 output rows per block
constexpr int BPB     = 64;                    // blocks per batch
// A/B vs R6: CONTIGUOUS row ownership (block j owns rows [32j, 32j+32) of its
// batch -> 48 KB sequential writes, max DRAM page locality) instead of
// 1-row interleave. Everything else unchanged.

typedef float  f32x4 __attribute__((ext_vector_type(4)));
typedef int    i32x4 __attribute__((ext_vector_type(4)));

__global__ __launch_bounds__(NTHR, 8) void lr_kernel(   // VGPR<=64: 8 blocks/CU resident
    const f32x4* __restrict__ x4,       // [B][N][D4]
    const int*   __restrict__ dur,      // [B][N]
    f32x4*       __restrict__ out4,     // [B][MD][D4]
    float*       __restrict__ out_total) // [B]
{
    __shared__ int cum[N_];             // 1 KB: this batch's inclusive cumsum
    __shared__ int srcrow[ROWS];        // per owned row: source row or -1 (zero row)

    const int t = threadIdx.x;
    // XCD-chunked bijective swizzle (2048 % 8 == 0): each batch's 64 blocks
    // land on one XCD -> its 396 KB x-slice stays in that XCD's L2.
    const int bid = ((blockIdx.x & 7) << 8) + (blockIdx.x >> 3);
    const int b   = bid >> 6;           // batch
    const int j   = bid & (BPB - 1);    // block index within batch

    // --- wave 0: inclusive cumsum of this batch's 256 durations
    if (t < 64) {
        i32x4 dv = reinterpret_cast<const i32x4*>(dur)[b * (N_ / 4) + t];
        int s0 = dv.x;
        int s1 = s0 + dv.y;
        int s2 = s1 + dv.z;
        int s3 = s2 + dv.w;
        int s = s3;
        #pragma unroll
        for (int o = 1; o < 64; o <<= 1) {
            int u = __shfl_up(s, o);    // wave64 inclusive scan of 4-chunk sums
            if (t >= o) s += u;
        }
        const int excl = s - s3;        // exclusive prefix for this lane's chunk
        i32x4 c4; c4.x = s0 + excl; c4.y = s1 + excl; c4.z = s2 + excl; c4.w = s3 + excl;
        reinterpret_cast<i32x4*>(cum)[t] = c4;
    }
    // --- wave 0, lanes 0-31: one binary search per owned row (pos = 32j + t)
    //     (same-wave LDS RAW on cum[]: compiler inserts lgkmcnt wait)
    if (t < ROWS) {
        const int pos = j * ROWS + t;
        const int total_b = cum[N_ - 1];
        int lo = 0;
        #pragma unroll
        for (int w = 128; w > 0; w >>= 1) {    // lo = count of cum[] <= pos
            if (cum[lo + w - 1] <= pos) lo += w;
        }
        srcrow[t] = (pos < total_b) ? lo : -1; // pos<total => lo<=255
        if (t == 0 && j == 0) {
            out_total[b] = (float)total_b;
        }
    }
    __syncthreads();

    // --- gather/zero-fill 32 contiguous rows: block writes one 48 KB
    //     sequential region (flat float4 range [bid*CHUNK, bid*CHUNK+3072)).
    const f32x4* __restrict__ xb = x4 + (size_t)b * (N_ * D4_);
    const int base = bid * CHUNK;
    #pragma unroll
    for (int i = 0; i < CHUNK / NTHR; ++i) {   // 12 iterations
        const int li = i * NTHR + t;           // 0..3071 within block
        const int q  = ((li >> 5) * 43) >> 7;  // == li/96 for li<3072 (local row)
        const int d4 = li - q * D4_;
        const int r  = srcrow[q];              // broadcast LDS read (<=2 rows/wave)
        f32x4 v = (f32x4)0.f;
        if (r >= 0) v = xb[r * D4_ + d4];      // predicated: no loads in zero rows
        out4[base + li] = v;                   // sequential streaming write
    }
}

extern "C" void kernel_launch(void* const* d_in, const int* in_sizes, int n_in,
                              void* d_out, int out_size, void* d_ws, size_t ws_size,
                              hipStream_t stream) {
    const f32x4* x4  = (const f32x4*)d_in[0];
    const int*   dur = (const int*)d_in[1];
    // d_in[2] = max_dur scalar (2048, fixed by the problem instance)

    float* out       = (float*)d_out;
    float* out_total = out + (size_t)B_ * MD_ * D_;  // totals appended after out
    f32x4* out4      = (f32x4*)d_out;

    lr_kernel<<<NBLK, NTHR, 0, stream>>>(x4, dur, out4, out_total);
}